// Round 16
// baseline (129.189 us; speedup 1.0000x reference)
//
#include <hip/hip_runtime.h>
#include <hip/hip_bf16.h>

typedef __bf16 bf16x8 __attribute__((ext_vector_type(8)));
typedef float f32x4 __attribute__((ext_vector_type(4)));
typedef unsigned int u32;
typedef u32 u32x4 __attribute__((ext_vector_type(4)));

#define MFMA(a, b, c) __builtin_amdgcn_mfma_f32_16x16x32_bf16((a), (b), (c), 0, 0, 0)

static __device__ __forceinline__ bf16x8 ld8(const __bf16* p) {
  return *reinterpret_cast<const bf16x8*>(p);
}

// pack two f32 -> bf16x2 in one u32 (compiler fuses to v_cvt_pk_bf16_f32)
static __device__ __forceinline__ u32 pkbf(float a, float b) {
  union { __bf16 h; unsigned short s; } x, y;
  x.h = (__bf16)a; y.h = (__bf16)b;
  return (u32)x.s | ((u32)y.s << 16);
}

// async global->LDS, 16B per lane; LDS dest is wave-uniform base + lane*16
typedef unsigned int __attribute__((address_space(1))) gu32_t;
typedef unsigned int __attribute__((address_space(3))) lu32_t;
static __device__ __forceinline__ void gld16(const __bf16* g, __bf16* l) {
  __builtin_amdgcn_global_load_lds((const gu32_t*)(const void*)g,
                                   (lu32_t*)(void*)l, 16, 0, 0);
}

// fp32 -> bf16 conversion for x and W_qkv (exact-fit into d_out region)
__global__ __launch_bounds__(256)
void cvt_f32_bf16(const float* __restrict__ a, __bf16* __restrict__ oa, int na,
                  const float* __restrict__ b, __bf16* __restrict__ ob) {
  const int i = blockIdx.x * 256 + threadIdx.x;  // one 8-elem chunk per thread
  const float* src; __bf16* dst; int e;
  if (i < (na >> 3)) { src = a; dst = oa; e = i << 3; }
  else { src = b; dst = ob; e = (i << 3) - na; }
  f32x4 v0 = *reinterpret_cast<const f32x4*>(src + e);
  f32x4 v1 = *reinterpret_cast<const f32x4*>(src + e + 4);
  bf16x8 o;
#pragma unroll
  for (int j = 0; j < 4; ++j) { o[j] = (__bf16)v0[j]; o[j + 4] = (__bf16)v1[j]; }
  *reinterpret_cast<bf16x8*>(dst + e) = o;
}

// 8 fp32 -> 8 bf16 LDS write (16B)
static __device__ __forceinline__ void stage8f(__bf16* __restrict__ dst,
                                               const float* __restrict__ src) {
  f32x4 a = *reinterpret_cast<const f32x4*>(src);
  f32x4 b = *reinterpret_cast<const f32x4*>(src + 4);
  bf16x8 o;
#pragma unroll
  for (int i = 0; i < 4; ++i) { o[i] = (__bf16)a[i]; o[i + 4] = (__bf16)b[i]; }
  *reinterpret_cast<bf16x8*>(dst) = o;
}

// C[m][n] = sum_k A[m][k] * W[n][k]  (A @ W^T).  BM=128, BK=64, BN template.
// A bf16 via global_load_lds(16B), pre-swizzled source (chunk ^= row&7).
// W: bf16 via gld16 (same swizzle) or fp32 via reg-stage + swizzled ds_write.
// 4 waves 2x2; wave tile 64 x BN/2. XCD-aware bijective block swizzle
// (grid%8==0): panel-sharing blocks land on the same XCD L2.
// SPLIT (GEMM1): Q cols scaled by SC2Q;
// cols [0,2048) -> QK buf; [2048,3072) -> VT[b*1024+col-2048][t].
template<int BN, bool SPLIT, bool OUT_BF16, bool B_F32>
__global__ __launch_bounds__(256, 2)
void gemm3(const __bf16* __restrict__ A, const void* __restrict__ Wv,
           void* __restrict__ Cv, __bf16* __restrict__ VT,
           int M, int N, int K) {
  constexpr int NF = BN / 32;  // B frags per wave per kc
  constexpr float SC2Q = 0.125f * 1.4426950408889634f;
  __shared__ __bf16 lA[128 * 64];
  __shared__ __bf16 lB[BN * 64];

  const int tid = threadIdx.x;
  const int ntiles = N / BN;
  // XCD-aware bijective swizzle (T1): valid because gridDim.x % 8 == 0
  const int per = gridDim.x >> 3;
  const int bid = (blockIdx.x & 7) * per + (blockIdx.x >> 3);
  const int mt = bid / ntiles;
  const int nt = bid % ntiles;
  const int m0 = mt << 7, n0 = nt * BN;
  const int lane = tid & 63, w = tid >> 6;
  const int wm = (w >> 1) << 6;
  const int wn = (w & 1) * (BN / 2);
  const int fr = lane & 15, fg = lane >> 4;

  f32x4 acc[4][NF] = {};

  for (int k0 = 0; k0 < K; k0 += 64) {
    __syncthreads();
#pragma unroll
    for (int jj = 0; jj < 4; ++jj) {
      const int q = (w << 2) | jj;
      const int v = (q << 6) | lane;
      const int row = v >> 3;
      const int cc = (v & 7) ^ (row & 7);
      gld16(A + (size_t)(m0 + row) * K + k0 + (cc << 3), lA + (q << 9));
    }
    if constexpr (B_F32) {
#pragma unroll
      for (int hh = 0; hh < BN / 64; ++hh) {
        const int row = (tid >> 2) + (hh << 6);
        const int c0 = (tid & 3) << 1;
        const float* src = (const float*)Wv + (size_t)(n0 + row) * K + k0 + (c0 << 3);
#pragma unroll
        for (int cg = 0; cg < 2; ++cg)
          stage8f(lB + (row << 6) + (((c0 + cg) ^ (row & 7)) << 3), src + (cg << 3));
      }
    } else {
#pragma unroll
      for (int jj = 0; jj < NF; ++jj) {
        const int q = w * NF + jj;
        const int v = (q << 6) | lane;
        const int row = v >> 3;
        const int cc = (v & 7) ^ (row & 7);
        gld16((const __bf16*)Wv + (size_t)(n0 + row) * K + k0 + (cc << 3), lB + (q << 9));
      }
    }
    __syncthreads();

    bf16x8 af[2][4], bfr[2][NF];
#pragma unroll
    for (int kc = 0; kc < 2; ++kc) {
#pragma unroll
      for (int m = 0; m < 4; ++m) {
        const int row = wm + m * 16 + fr;
        af[kc][m] = ld8(lA + (row << 6) + ((((kc << 2) | fg) ^ (row & 7)) << 3));
      }
#pragma unroll
      for (int n = 0; n < NF; ++n) {
        const int row = wn + n * 16 + fr;
        bfr[kc][n] = ld8(lB + (row << 6) + ((((kc << 2) | fg) ^ (row & 7)) << 3));
      }
    }
#pragma unroll
    for (int kc = 0; kc < 2; ++kc)
#pragma unroll
      for (int m = 0; m < 4; ++m)
#pragma unroll
        for (int n = 0; n < NF; ++n)
          acc[m][n] = MFMA(af[kc][m], bfr[kc][n], acc[m][n]);
  }

  // C/D layout: col = lane&15, row = (lane>>4)*4 + reg
#pragma unroll
  for (int m = 0; m < 4; ++m) {
#pragma unroll
    for (int n = 0; n < NF; ++n) {
#pragma unroll
      for (int r = 0; r < 4; ++r) {
        int row = m0 + wm + m * 16 + fg * 4 + r;
        int col = n0 + wn + n * 16 + fr;
        float v = acc[m][n][r];
        if constexpr (SPLIT) {
          int b = row >> 11, t = row & 2047;
          if (col >= 2048) {
            VT[((size_t)(b << 10) + (col - 2048)) * 2048 + t] = (__bf16)v;
          } else {
            if (col < 1024) v *= SC2Q;  // pre-scale Q for attention
            ((__bf16*)Cv)[(size_t)row * 2048 + col] = (__bf16)v;
          }
        } else if constexpr (OUT_BF16) {
          ((__bf16*)Cv)[(size_t)row * N + col] = (__bf16)v;
        } else {
          ((float*)Cv)[(size_t)row * N + col] = v;
        }
      }
    }
  }
}

// One online-softmax step for a 64-key tile held as S^T fragments.
// s[n][r] = S[key=k0+n*16+fg*4+r][q=q0wt+fr] (already scaled, log2 domain).
static __device__ __forceinline__ void softmax_step(
    f32x4 (&s)[4], f32x4 (&o)[4], float& m, float& l, bf16x8 (&pa)[2],
    bool diag, int q0wt, int k0, int fg, int fr) {
  constexpr float NEG = -1e30f;
  float sv[4][4];
#pragma unroll
  for (int n = 0; n < 4; ++n)
#pragma unroll
    for (int r = 0; r < 4; ++r) {
      float x = s[n][r];
      if (diag && (k0 + n * 16 + fg * 4 + r > q0wt + fr)) x = NEG;
      sv[n][r] = x;
    }

  float t0 = fmaxf(fmaxf(sv[0][0], sv[0][1]), fmaxf(sv[0][2], sv[0][3]));
  float t1 = fmaxf(fmaxf(sv[1][0], sv[1][1]), fmaxf(sv[1][2], sv[1][3]));
  float t2 = fmaxf(fmaxf(sv[2][0], sv[2][1]), fmaxf(sv[2][2], sv[2][3]));
  float t3 = fmaxf(fmaxf(sv[3][0], sv[3][1]), fmaxf(sv[3][2], sv[3][3]));
  float rm = fmaxf(fmaxf(t0, t1), fmaxf(t2, t3));
  rm = fmaxf(rm, __shfl_xor(rm, 16));
  rm = fmaxf(rm, __shfl_xor(rm, 32));

  // defer-max (T13): rescale only when tile max pushes past m+16
  if (!__all(rm <= m + 16.f)) {
    float mnew = fmaxf(m, rm);
    float alpha = __builtin_exp2f(m - mnew);
    m = mnew;
    l *= alpha;
    float ao[4];
#pragma unroll
    for (int r = 0; r < 4; ++r)
      ao[r] = __shfl(alpha, fg * 4 + r);
#pragma unroll
    for (int n = 0; n < 4; ++n)
#pragma unroll
      for (int r = 0; r < 4; ++r)
        o[n][r] *= ao[r];
  }

  float p[4][4];
#pragma unroll
  for (int n = 0; n < 4; ++n)
#pragma unroll
    for (int r = 0; r < 4; ++r)
      p[n][r] = __builtin_exp2f(sv[n][r] - m);

  float u0 = (p[0][0] + p[0][1]) + (p[0][2] + p[0][3]);
  float u1 = (p[1][0] + p[1][1]) + (p[1][2] + p[1][3]);
  float u2 = (p[2][0] + p[2][1]) + (p[2][2] + p[2][3]);
  float u3 = (p[3][0] + p[3][1]) + (p[3][2] + p[3][3]);
  float rs = (u0 + u1) + (u2 + u3);
  rs += __shfl_xor(rs, 16);
  rs += __shfl_xor(rs, 32);
  l += rs;

  u32 wpk[4][2];
#pragma unroll
  for (int n = 0; n < 4; ++n) {
    wpk[n][0] = pkbf(p[n][0], p[n][1]);
    wpk[n][1] = pkbf(p[n][2], p[n][3]);
  }

  // redistribute P^T -> PV A-fragments (8 bpermutes; bijective instances)
  u32 rcv[2][2][2];
#pragma unroll
  for (int e = 0; e < 2; ++e) {
    const int src = fr + ((((fg & 1) << 1) | ((fg >> 1) ^ e)) << 4);
    const bool tsel = ((fg & 1) ^ e) != 0;
#pragma unroll
    for (int c = 0; c < 2; ++c)
#pragma unroll
      for (int hh = 0; hh < 2; ++hh) {
        u32 v = tsel ? wpk[(c << 1) | 1][hh] : wpk[(c << 1) | 0][hh];
        rcv[e][c][hh] = (u32)__shfl((int)v, src);
      }
  }
  const bool hi = (fg >> 1) != 0;
  u32x4 w0, w1;
#pragma unroll
  for (int a = 0; a < 2; ++a)
#pragma unroll
    for (int hh = 0; hh < 2; ++hh) {
      w0[2 * a + hh] = hi ? rcv[a ^ 1][0][hh] : rcv[a][0][hh];
      w1[2 * a + hh] = hi ? rcv[a ^ 1][1][hh] : rcv[a][1][hh];
    }
  pa[0] = __builtin_bit_cast(bf16x8, w0);
  pa[1] = __builtin_bit_cast(bf16x8, w1);
}

static __device__ __forceinline__ void write_out(
    __bf16* __restrict__ out, f32x4 (&o)[4], float l,
    int b, int hoff, int q0wt, int fg, int fr) {
  float linv = 1.f / l;
  float lo[4];
#pragma unroll
  for (int r = 0; r < 4; ++r)
    lo[r] = __shfl(linv, fg * 4 + r);
#pragma unroll
  for (int n = 0; n < 4; ++n)
#pragma unroll
    for (int r = 0; r < 4; ++r) {
      int t = q0wt + fg * 4 + r;
      out[((size_t)(b * 2048 + t)) * 1024 + hoff + n * 16 + fr] = (__bf16)(o[n][r] * lo[r]);
    }
}

// FA2-style causal flash attention, 1280 blocks (5 blocks/CU: fills the 5th
// LDS slot that grid=1024 left empty).
// Tasks qb<=23 run unsplit (R10-proven body, stride-1). Tasks qb in [24,31]
// are split into 2 key-parity blocks (kt = p, p+2, ... — R8-proven stride-2
// staging/softmax); p=0 writes its normalized partial into the final attn
// slice, p=1 into pb1 (d_out tail), stats (m + log2 l, f32) into sbuf.
// attn_combine16 flash-merges the 256 split tasks afterwards.
// Block map: bh = ((blk&7)<<2)|((blk>>3)&3); band jb = blk>>5:
//   jb 0..7   -> unsplit qb = 23-jb        (24..17 iters, longest first)
//   jb 8..23  -> split   qb = 31-((jb-8)>>1), p = (jb-8)&1  (16..13 iters)
//   jb 24..39 -> unsplit qb = 15-(jb-24)   (16..1 iters)
// Q pre-scaled by 0.125*log2(e) in GEMM1.
__global__ __launch_bounds__(256, 5)
void attn_causal16(const __bf16* __restrict__ qk, const __bf16* __restrict__ vt,
                   __bf16* __restrict__ attn, __bf16* __restrict__ pb1,
                   float* __restrict__ sbuf) {
  constexpr float NEG = -1e30f;

  __shared__ __bf16 lK[2][4096];  // [buf][key(64) x dkchunk(8) x 8]
  __shared__ __bf16 lV[2][4096];  // [buf][dk(64) x keychunk(8) x 8]

  const int tid = threadIdx.x;
  const int lane = tid & 63, w = tid >> 6;
  const int fr = lane & 15, fg = lane >> 4;
  const int blk = blockIdx.x;
  const int bh = ((blk & 7) << 2) | ((blk >> 3) & 3);  // XCD-local bh group
  const int jb = blk >> 5;                             // 0..39
  int qb, p0, st;
  bool split;
  if (jb < 8) { qb = 23 - jb; p0 = 0; st = 1; split = false; }
  else if (jb < 24) { int sj = jb - 8; qb = 31 - (sj >> 1); p0 = sj & 1; st = 2; split = true; }
  else { qb = 15 - (jb - 24); p0 = 0; st = 1; split = false; }

  const int b = bh >> 4, h = bh & 15;
  const int q0w = (qb << 6) + (w << 4);       // this wave's q base
  const int hoff = h * 64;
  const size_t qkbase = (size_t)b * (2048 * 2048);
  const __bf16* kb = qk + qkbase + 1024 + hoff;                // K rows, stride 2048
  const __bf16* vtb = vt + (size_t)((b << 10) | hoff) * 2048;  // V^T rows, stride 2048

  // Q fragments (B-operand): col = fr = q-row, k = c*32 + fg*8 + i
  bf16x8 qf[2];
#pragma unroll
  for (int c = 0; c < 2; ++c)
    qf[c] = ld8(qk + qkbase + (size_t)(q0w + fr) * 2048 + hoff + c * 32 + fg * 8);

  f32x4 o[4] = {};
  float m = NEG;
  float l = 0.f;

#define STAGE(bf, k0s)                                                        \
  do {                                                                        \
    _Pragma("unroll")                                                         \
    for (int jj = 0; jj < 2; ++jj) {                                          \
      const int q = (w << 1) | jj;                                            \
      const int v = (q << 6) | lane;                                          \
      const int row = v >> 3;                                                 \
      const int cc = (v & 7) ^ (row & 7);                                     \
      gld16(kb + (size_t)((k0s) + row) * 2048 + (cc << 3), &lK[bf][q << 9]);  \
      gld16(vtb + (size_t)row * 2048 + (k0s) + (cc << 3), &lV[bf][q << 9]);   \
    }                                                                         \
  } while (0)

  int buf = 0;
  STAGE(0, p0 << 6);
  __syncthreads();

  for (int kt = p0; kt <= qb; kt += st) {
    const int k0 = kt << 6;
    if (kt + st <= qb) STAGE(buf ^ 1, (kt + st) << 6);  // prefetch next tile

    // QK on LDS K: s[n][r] = S[key=k0+n*16+fg*4+r][q=q0w+fr] (pre-scaled)
    f32x4 s[4] = {};
#pragma unroll
    for (int c = 0; c < 2; ++c) {
      bf16x8 kfc[4];
#pragma unroll
      for (int n = 0; n < 4; ++n) {
        const int row = n * 16 + fr;
        const int sc = ((c << 2) | fg) ^ (row & 7);
        kfc[n] = ld8(&lK[buf][(row << 6) + (sc << 3)]);
      }
#pragma unroll
      for (int n = 0; n < 4; ++n)
        s[n] = MFMA(kfc[n], qf[c], s[n]);
    }

    bf16x8 pa[2];
    softmax_step(s, o, m, l, pa, kt == qb, q0w, k0, fg, fr);

    // O += P V from LDS V^T: B-frag row = dk = n*16+fr, key chunk = c*4+fg
#pragma unroll
    for (int c = 0; c < 2; ++c) {
      bf16x8 vfc[4];
#pragma unroll
      for (int n = 0; n < 4; ++n) {
        const int row = n * 16 + fr;
        const int sc = ((c << 2) | fg) ^ (row & 7);
        vfc[n] = ld8(&lV[buf][(row << 6) + (sc << 3)]);
      }
#pragma unroll
      for (int n = 0; n < 4; ++n)
        o[n] = MFMA(pa[c], vfc[n], o[n]);
    }

    __syncthreads();  // all waves done reading buf; vmcnt drained (next staged)
    buf ^= 1;
  }
#undef STAGE

  if (!split) {
    write_out(attn, o, l, b, hoff, q0w, fg, fr);
  } else {
    const int ti = ((31 - qb) << 5) | bh;       // split-task index 0..255
    const float s_stat = m + __log2f(l);        // log2-domain flash stat
    if (p0 == 0) {
      // normalized partial straight into the final attn slice
      write_out(attn, o, l, b, hoff, q0w, fg, fr);
      if (fg == 0) sbuf[ti * 64 + w * 16 + fr] = s_stat;
    } else {
      float linv = 1.f / l;
      float lo[4];
#pragma unroll
      for (int r = 0; r < 4; ++r)
        lo[r] = __shfl(linv, fg * 4 + r);
#pragma unroll
      for (int n = 0; n < 4; ++n)
#pragma unroll
        for (int r = 0; r < 4; ++r)
          pb1[(size_t)ti * 4096 + (w * 16 + fg * 4 + r) * 64 + n * 16 + fr] =
              (__bf16)(o[n][r] * lo[r]);
      if (fg == 0) sbuf[16384 + ti * 64 + w * 16 + fr] = s_stat;
    }
  }
}

// Flash-merge of the 256 split tasks: attn_slice = (w0*O0n + w1*O1n)/(w0+w1),
// w_p = 2^(s_p - smax). Thread u -> (ti, row, dk-octet); in-place on attn.
__global__ __launch_bounds__(256)
void attn_combine16(const __bf16* __restrict__ pb1, const float* __restrict__ sbuf,
                    __bf16* __restrict__ attn) {
  const int u = blockIdx.x * 256 + threadIdx.x;  // 0..131071
  const int ti = u >> 9;          // task 0..255
  const int rw = (u >> 3) & 63;   // row within task
  const int d8 = (u & 7) << 3;    // dk octet base
  const int qb = 31 - (ti >> 5), bh = ti & 31;
  const int b = bh >> 4, h = bh & 15;
  const int t = (qb << 6) + rw;

  const float s0 = sbuf[ti * 64 + rw];
  const float s1 = sbuf[16384 + ti * 64 + rw];
  const float sm = fmaxf(s0, s1);
  float w0 = __builtin_exp2f(s0 - sm), w1 = __builtin_exp2f(s1 - sm);
  const float inv = 1.f / (w0 + w1);
  w0 *= inv; w1 *= inv;

  __bf16* dst = attn + ((size_t)(b * 2048 + t)) * 1024 + h * 64 + d8;
  bf16x8 a = ld8(dst);
  bf16x8 c = ld8(pb1 + (size_t)ti * 4096 + rw * 64 + d8);
  bf16x8 o;
#pragma unroll
  for (int e = 0; e < 8; ++e)
    o[e] = (__bf16)(w0 * (float)a[e] + w1 * (float)c[e]);
  *reinterpret_cast<bf16x8*>(dst) = o;
}

extern "C" void kernel_launch(void* const* d_in, const int* in_sizes, int n_in,
                              void* d_out, int out_size, void* d_ws, size_t ws_size,
                              hipStream_t stream) {
  const float* x = (const float*)d_in[0];       // (2,2048,1024) fp32
  const float* w_qkv = (const float*)d_in[1];   // (3072,1024) fp32
  const float* w_o = (const float*)d_in[2];     // (1024,1024) fp32
  float* out = (float*)d_out;                   // (2,2048,1024) fp32

  const int M = 4096;  // B*T
  __bf16* qk = (__bf16*)d_ws;                                    // 4096 x 2048 bf16 (16MB)
  __bf16* vt = (__bf16*)((char*)d_ws + (size_t)M * 2048 * 2);    // 2048 x 2048 bf16 (8MB)
  __bf16* attn = (__bf16*)((char*)d_ws + (size_t)M * 3072 * 2);  // 4096 x 1024 bf16 (8MB)
  float* sbuf = (float*)((char*)d_ws + 33554432);                // 128KB stats (R8-proven region)

  // d_out layout (dead until GEMM2 writes out): xb 8.39MB + wqb 6.29MB +
  // pb1 2.10MB = 16.78MB exact.
  __bf16* xb = (__bf16*)d_out;
  __bf16* wqb = xb + 4194304;
  __bf16* pb1 = wqb + 3145728;   // 256 tasks x 4096 bf16 partials
  const int NX = 4194304;        // x elems

  cvt_f32_bf16<<<3584, 256, 0, stream>>>(x, xb, NX, w_qkv, wqb);

  // GEMM1: qkv = x @ W_qkv^T ; Q (pre-scaled), K -> qk, V -> vt transposed
  gemm3<128, true, true, false><<<(M / 128) * (3072 / 128), 256, 0, stream>>>(
      xb, (const void*)wqb, (void*)qk, vt, M, 3072, 1024);

  // causal attention: 1280 blocks (5/CU; long tasks key-parity split)
  attn_causal16<<<1280, 256, 0, stream>>>(qk, vt, attn, pb1, sbuf);

  // merge the 256 split tasks' parity halves
  attn_combine16<<<512, 256, 0, stream>>>(pb1, sbuf, attn);

  // GEMM2: out = attn @ W_o^T (BN=64 tiles: 512 blocks)
  gemm3<64, false, false, true><<<(M / 128) * (1024 / 64), 256, 0, stream>>>(
      attn, (const void*)w_o, (void*)out, nullptr, M, 1024, 1024);
}

// Round 17
// 119.461 us; speedup vs baseline: 1.0814x; 1.0814x over previous
//
#include <hip/hip_runtime.h>
#include <hip/hip_bf16.h>

typedef __bf16 bf16x8 __attribute__((ext_vector_type(8)));
typedef float f32x4 __attribute__((ext_vector_type(4)));
typedef unsigned int u32;
typedef u32 u32x4 __attribute__((ext_vector_type(4)));

#define MFMA(a, b, c) __builtin_amdgcn_mfma_f32_16x16x32_bf16((a), (b), (c), 0, 0, 0)

static __device__ __forceinline__ bf16x8 ld8(const __bf16* p) {
  return *reinterpret_cast<const bf16x8*>(p);
}

// pack two f32 -> bf16x2 in one u32 (compiler fuses to v_cvt_pk_bf16_f32)
static __device__ __forceinline__ u32 pkbf(float a, float b) {
  union { __bf16 h; unsigned short s; } x, y;
  x.h = (__bf16)a; y.h = (__bf16)b;
  return (u32)x.s | ((u32)y.s << 16);
}

// async global->LDS, 16B per lane; LDS dest is wave-uniform base + lane*16
typedef unsigned int __attribute__((address_space(1))) gu32_t;
typedef unsigned int __attribute__((address_space(3))) lu32_t;
static __device__ __forceinline__ void gld16(const __bf16* g, __bf16* l) {
  __builtin_amdgcn_global_load_lds((const gu32_t*)(const void*)g,
                                   (lu32_t*)(void*)l, 16, 0, 0);
}

// fp32 -> bf16 conversion for x and W_qkv (exact-fit into d_out region)
__global__ __launch_bounds__(256)
void cvt_f32_bf16(const float* __restrict__ a, __bf16* __restrict__ oa, int na,
                  const float* __restrict__ b, __bf16* __restrict__ ob) {
  const int i = blockIdx.x * 256 + threadIdx.x;  // one 8-elem chunk per thread
  const float* src; __bf16* dst; int e;
  if (i < (na >> 3)) { src = a; dst = oa; e = i << 3; }
  else { src = b; dst = ob; e = (i << 3) - na; }
  f32x4 v0 = *reinterpret_cast<const f32x4*>(src + e);
  f32x4 v1 = *reinterpret_cast<const f32x4*>(src + e + 4);
  bf16x8 o;
#pragma unroll
  for (int j = 0; j < 4; ++j) { o[j] = (__bf16)v0[j]; o[j + 4] = (__bf16)v1[j]; }
  *reinterpret_cast<bf16x8*>(dst + e) = o;
}

// 8 fp32 -> 8 bf16 LDS write (16B)
static __device__ __forceinline__ void stage8f(__bf16* __restrict__ dst,
                                               const float* __restrict__ src) {
  f32x4 a = *reinterpret_cast<const f32x4*>(src);
  f32x4 b = *reinterpret_cast<const f32x4*>(src + 4);
  bf16x8 o;
#pragma unroll
  for (int i = 0; i < 4; ++i) { o[i] = (__bf16)a[i]; o[i + 4] = (__bf16)b[i]; }
  *reinterpret_cast<bf16x8*>(dst) = o;
}

// C[m][n] = sum_k A[m][k] * W[n][k]  (A @ W^T).  BM=128, BK=64, BN template.
// A bf16 via global_load_lds(16B), pre-swizzled source (chunk ^= row&7).
// W: bf16 via gld16 (same swizzle) or fp32 via reg-stage + swizzled ds_write.
// 4 waves 2x2; wave tile 64 x BN/2. XCD-aware bijective block swizzle
// (grid%8==0): panel-sharing blocks land on the same XCD L2.
// SPLIT (GEMM1): Q cols scaled by SC2Q;
// cols [0,2048) -> QK buf; [2048,3072) -> VT[b*1024+col-2048][t].
template<int BN, bool SPLIT, bool OUT_BF16, bool B_F32>
__global__ __launch_bounds__(256, 2)
void gemm3(const __bf16* __restrict__ A, const void* __restrict__ Wv,
           void* __restrict__ Cv, __bf16* __restrict__ VT,
           int M, int N, int K) {
  constexpr int NF = BN / 32;  // B frags per wave per kc
  constexpr float SC2Q = 0.125f * 1.4426950408889634f;
  __shared__ __bf16 lA[128 * 64];
  __shared__ __bf16 lB[BN * 64];

  const int tid = threadIdx.x;
  const int ntiles = N / BN;
  // XCD-aware bijective swizzle (T1): valid because gridDim.x % 8 == 0
  const int per = gridDim.x >> 3;
  const int bid = (blockIdx.x & 7) * per + (blockIdx.x >> 3);
  const int mt = bid / ntiles;
  const int nt = bid % ntiles;
  const int m0 = mt << 7, n0 = nt * BN;
  const int lane = tid & 63, w = tid >> 6;
  const int wm = (w >> 1) << 6;
  const int wn = (w & 1) * (BN / 2);
  const int fr = lane & 15, fg = lane >> 4;

  f32x4 acc[4][NF] = {};

  for (int k0 = 0; k0 < K; k0 += 64) {
    __syncthreads();
#pragma unroll
    for (int jj = 0; jj < 4; ++jj) {
      const int q = (w << 2) | jj;
      const int v = (q << 6) | lane;
      const int row = v >> 3;
      const int cc = (v & 7) ^ (row & 7);
      gld16(A + (size_t)(m0 + row) * K + k0 + (cc << 3), lA + (q << 9));
    }
    if constexpr (B_F32) {
#pragma unroll
      for (int hh = 0; hh < BN / 64; ++hh) {
        const int row = (tid >> 2) + (hh << 6);
        const int c0 = (tid & 3) << 1;
        const float* src = (const float*)Wv + (size_t)(n0 + row) * K + k0 + (c0 << 3);
#pragma unroll
        for (int cg = 0; cg < 2; ++cg)
          stage8f(lB + (row << 6) + (((c0 + cg) ^ (row & 7)) << 3), src + (cg << 3));
      }
    } else {
#pragma unroll
      for (int jj = 0; jj < NF; ++jj) {
        const int q = w * NF + jj;
        const int v = (q << 6) | lane;
        const int row = v >> 3;
        const int cc = (v & 7) ^ (row & 7);
        gld16((const __bf16*)Wv + (size_t)(n0 + row) * K + k0 + (cc << 3), lB + (q << 9));
      }
    }
    __syncthreads();

    bf16x8 af[2][4], bfr[2][NF];
#pragma unroll
    for (int kc = 0; kc < 2; ++kc) {
#pragma unroll
      for (int m = 0; m < 4; ++m) {
        const int row = wm + m * 16 + fr;
        af[kc][m] = ld8(lA + (row << 6) + ((((kc << 2) | fg) ^ (row & 7)) << 3));
      }
#pragma unroll
      for (int n = 0; n < NF; ++n) {
        const int row = wn + n * 16 + fr;
        bfr[kc][n] = ld8(lB + (row << 6) + ((((kc << 2) | fg) ^ (row & 7)) << 3));
      }
    }
#pragma unroll
    for (int kc = 0; kc < 2; ++kc)
#pragma unroll
      for (int m = 0; m < 4; ++m)
#pragma unroll
        for (int n = 0; n < NF; ++n)
          acc[m][n] = MFMA(af[kc][m], bfr[kc][n], acc[m][n]);
  }

  // C/D layout: col = lane&15, row = (lane>>4)*4 + reg
#pragma unroll
  for (int m = 0; m < 4; ++m) {
#pragma unroll
    for (int n = 0; n < NF; ++n) {
#pragma unroll
      for (int r = 0; r < 4; ++r) {
        int row = m0 + wm + m * 16 + fg * 4 + r;
        int col = n0 + wn + n * 16 + fr;
        float v = acc[m][n][r];
        if constexpr (SPLIT) {
          int b = row >> 11, t = row & 2047;
          if (col >= 2048) {
            VT[((size_t)(b << 10) + (col - 2048)) * 2048 + t] = (__bf16)v;
          } else {
            if (col < 1024) v *= SC2Q;  // pre-scale Q for attention
            ((__bf16*)Cv)[(size_t)row * 2048 + col] = (__bf16)v;
          }
        } else if constexpr (OUT_BF16) {
          ((__bf16*)Cv)[(size_t)row * N + col] = (__bf16)v;
        } else {
          ((float*)Cv)[(size_t)row * N + col] = v;
        }
      }
    }
  }
}

// One online-softmax step for a 64-key tile held as S^T fragments.
// s[n][r] = S[key=k0+n*16+fg*4+r][q=q0wt+fr] (already scaled, log2 domain).
static __device__ __forceinline__ void softmax_step(
    f32x4 (&s)[4], f32x4 (&o)[4], float& m, float& l, bf16x8 (&pa)[2],
    bool diag, int q0wt, int k0, int fg, int fr) {
  constexpr float NEG = -1e30f;
  float sv[4][4];
#pragma unroll
  for (int n = 0; n < 4; ++n)
#pragma unroll
    for (int r = 0; r < 4; ++r) {
      float x = s[n][r];
      if (diag && (k0 + n * 16 + fg * 4 + r > q0wt + fr)) x = NEG;
      sv[n][r] = x;
    }

  float t0 = fmaxf(fmaxf(sv[0][0], sv[0][1]), fmaxf(sv[0][2], sv[0][3]));
  float t1 = fmaxf(fmaxf(sv[1][0], sv[1][1]), fmaxf(sv[1][2], sv[1][3]));
  float t2 = fmaxf(fmaxf(sv[2][0], sv[2][1]), fmaxf(sv[2][2], sv[2][3]));
  float t3 = fmaxf(fmaxf(sv[3][0], sv[3][1]), fmaxf(sv[3][2], sv[3][3]));
  float rm = fmaxf(fmaxf(t0, t1), fmaxf(t2, t3));
  rm = fmaxf(rm, __shfl_xor(rm, 16));
  rm = fmaxf(rm, __shfl_xor(rm, 32));

  // defer-max (T13): rescale only when tile max pushes past m+16
  if (!__all(rm <= m + 16.f)) {
    float mnew = fmaxf(m, rm);
    float alpha = __builtin_exp2f(m - mnew);
    m = mnew;
    l *= alpha;
    float ao[4];
#pragma unroll
    for (int r = 0; r < 4; ++r)
      ao[r] = __shfl(alpha, fg * 4 + r);
#pragma unroll
    for (int n = 0; n < 4; ++n)
#pragma unroll
      for (int r = 0; r < 4; ++r)
        o[n][r] *= ao[r];
  }

  float p[4][4];
#pragma unroll
  for (int n = 0; n < 4; ++n)
#pragma unroll
    for (int r = 0; r < 4; ++r)
      p[n][r] = __builtin_exp2f(sv[n][r] - m);

  float u0 = (p[0][0] + p[0][1]) + (p[0][2] + p[0][3]);
  float u1 = (p[1][0] + p[1][1]) + (p[1][2] + p[1][3]);
  float u2 = (p[2][0] + p[2][1]) + (p[2][2] + p[2][3]);
  float u3 = (p[3][0] + p[3][1]) + (p[3][2] + p[3][3]);
  float rs = (u0 + u1) + (u2 + u3);
  rs += __shfl_xor(rs, 16);
  rs += __shfl_xor(rs, 32);
  l += rs;

  u32 wpk[4][2];
#pragma unroll
  for (int n = 0; n < 4; ++n) {
    wpk[n][0] = pkbf(p[n][0], p[n][1]);
    wpk[n][1] = pkbf(p[n][2], p[n][3]);
  }

  // redistribute P^T -> PV A-fragments (8 bpermutes; bijective instances)
  u32 rcv[2][2][2];
#pragma unroll
  for (int e = 0; e < 2; ++e) {
    const int src = fr + ((((fg & 1) << 1) | ((fg >> 1) ^ e)) << 4);
    const bool tsel = ((fg & 1) ^ e) != 0;
#pragma unroll
    for (int c = 0; c < 2; ++c)
#pragma unroll
      for (int hh = 0; hh < 2; ++hh) {
        u32 v = tsel ? wpk[(c << 1) | 1][hh] : wpk[(c << 1) | 0][hh];
        rcv[e][c][hh] = (u32)__shfl((int)v, src);
      }
  }
  const bool hi = (fg >> 1) != 0;
  u32x4 w0, w1;
#pragma unroll
  for (int a = 0; a < 2; ++a)
#pragma unroll
    for (int hh = 0; hh < 2; ++hh) {
      w0[2 * a + hh] = hi ? rcv[a ^ 1][0][hh] : rcv[a][0][hh];
      w1[2 * a + hh] = hi ? rcv[a ^ 1][1][hh] : rcv[a][1][hh];
    }
  pa[0] = __builtin_bit_cast(bf16x8, w0);
  pa[1] = __builtin_bit_cast(bf16x8, w1);
}

static __device__ __forceinline__ void write_out(
    __bf16* __restrict__ out, f32x4 (&o)[4], float l,
    int b, int hoff, int q0wt, int fg, int fr) {
  float linv = 1.f / l;
  float lo[4];
#pragma unroll
  for (int r = 0; r < 4; ++r)
    lo[r] = __shfl(linv, fg * 4 + r);
#pragma unroll
  for (int n = 0; n < 4; ++n)
#pragma unroll
    for (int r = 0; r < 4; ++r) {
      int t = q0wt + fg * 4 + r;
      out[((size_t)(b * 2048 + t)) * 1024 + hoff + n * 16 + fr] = (__bf16)(o[n][r] * lo[r]);
    }
}

// FA2-style causal flash attention (R10-proven schedule; Q pre-scaled).
// qk: (B*T, 2048) bf16, col = s(0=Q,1=K)*1024 + h*64 + dk (Q pre-scaled).
// vt: (B*1024, 2048) bf16 = V^T per (b,h): row b*1024 + h*64 + dk, col = t.
// Grid: 1024 blocks x 256. Block = (qb, bh): 64 q-rows, wave w owns rows
// [qb*64 + w*16, +16). K/V^T tiles (64x64 each) double-buffered in LDS via
// global_load_lds, chunk-XOR swizzled. One __syncthreads per tile;
// STAGE(next) issued before compute. In-register softmax via swapped QK^T.
__global__ __launch_bounds__(256, 4)
void attn_causal10(const __bf16* __restrict__ qk, const __bf16* __restrict__ vt,
                   __bf16* __restrict__ out) {
  constexpr float NEG = -1e30f;

  __shared__ __bf16 lK[2][4096];  // [buf][key(64) x dkchunk(8) x 8]
  __shared__ __bf16 lV[2][4096];  // [buf][dk(64) x keychunk(8) x 8]

  const int tid = threadIdx.x;
  const int lane = tid & 63, w = tid >> 6;
  const int fr = lane & 15, fg = lane >> 4;
  const int blk = blockIdx.x;
  const int j = blk >> 3;
  const int bh = ((blk & 7) << 2) | (j & 3);  // XCD-local bh group
  const int qb = 31 - (j >> 2);               // LPT: longest first
  const int b = bh >> 4, h = bh & 15;
  const int q0w = (qb << 6) + (w << 4);       // this wave's q base
  const int hoff = h * 64;
  const size_t qkbase = (size_t)b * (2048 * 2048);
  const __bf16* kb = qk + qkbase + 1024 + hoff;                // K rows, stride 2048
  const __bf16* vtb = vt + (size_t)((b << 10) | hoff) * 2048;  // V^T rows, stride 2048

  // Q fragments (B-operand): col = fr = q-row, k = c*32 + fg*8 + i
  bf16x8 qf[2];
#pragma unroll
  for (int c = 0; c < 2; ++c)
    qf[c] = ld8(qk + qkbase + (size_t)(q0w + fr) * 2048 + hoff + c * 32 + fg * 8);

  f32x4 o[4] = {};
  float m = NEG;
  float l = 0.f;

#define STAGE(bf, k0s)                                                        \
  do {                                                                        \
    _Pragma("unroll")                                                         \
    for (int jj = 0; jj < 2; ++jj) {                                          \
      const int q = (w << 1) | jj;                                            \
      const int v = (q << 6) | lane;                                          \
      const int row = v >> 3;                                                 \
      const int cc = (v & 7) ^ (row & 7);                                     \
      gld16(kb + (size_t)((k0s) + row) * 2048 + (cc << 3), &lK[bf][q << 9]);  \
      gld16(vtb + (size_t)row * 2048 + (k0s) + (cc << 3), &lV[bf][q << 9]);   \
    }                                                                         \
  } while (0)

  int buf = 0;
  STAGE(0, 0);
  __syncthreads();

  for (int kt = 0; kt <= qb; ++kt) {
    const int k0 = kt << 6;
    if (kt < qb) STAGE(buf ^ 1, k0 + 64);  // prefetch next tile (other buffer)

    // QK on LDS K: s[n][r] = S[key=k0+n*16+fg*4+r][q=q0w+fr] (pre-scaled)
    f32x4 s[4] = {};
#pragma unroll
    for (int c = 0; c < 2; ++c) {
      bf16x8 kfc[4];
#pragma unroll
      for (int n = 0; n < 4; ++n) {
        const int row = n * 16 + fr;
        const int sc = ((c << 2) | fg) ^ (row & 7);
        kfc[n] = ld8(&lK[buf][(row << 6) + (sc << 3)]);
      }
#pragma unroll
      for (int n = 0; n < 4; ++n)
        s[n] = MFMA(kfc[n], qf[c], s[n]);
    }

    bf16x8 pa[2];
    softmax_step(s, o, m, l, pa, kt == qb, q0w, k0, fg, fr);

    // O += P V from LDS V^T: B-frag row = dk = n*16+fr, key chunk = c*4+fg
#pragma unroll
    for (int c = 0; c < 2; ++c) {
      bf16x8 vfc[4];
#pragma unroll
      for (int n = 0; n < 4; ++n) {
        const int row = n * 16 + fr;
        const int sc = ((c << 2) | fg) ^ (row & 7);
        vfc[n] = ld8(&lV[buf][(row << 6) + (sc << 3)]);
      }
#pragma unroll
      for (int n = 0; n < 4; ++n)
        o[n] = MFMA(pa[c], vfc[n], o[n]);
    }

    __syncthreads();  // all waves done reading buf; vmcnt drained (next staged)
    buf ^= 1;
  }
#undef STAGE

  write_out(out, o, l, b, hoff, q0w, fg, fr);
}

extern "C" void kernel_launch(void* const* d_in, const int* in_sizes, int n_in,
                              void* d_out, int out_size, void* d_ws, size_t ws_size,
                              hipStream_t stream) {
  const float* x = (const float*)d_in[0];       // (2,2048,1024) fp32
  const float* w_qkv = (const float*)d_in[1];   // (3072,1024) fp32
  const float* w_o = (const float*)d_in[2];     // (1024,1024) fp32
  float* out = (float*)d_out;                   // (2,2048,1024) fp32

  const int M = 4096;  // B*T
  __bf16* qk = (__bf16*)d_ws;                                    // 4096 x 2048 bf16 (16MB)
  __bf16* vt = (__bf16*)((char*)d_ws + (size_t)M * 2048 * 2);    // 2048 x 2048 bf16 (8MB)
  __bf16* attn = (__bf16*)((char*)d_ws + (size_t)M * 3072 * 2);  // 4096 x 1024 bf16 (8MB)

  // bf16 copies of x and W_qkv live in d_out (dead until GEMM2 writes it)
  __bf16* xb = (__bf16*)d_out;
  __bf16* wqb = xb + 4194304;
  const int NX = 4194304;  // x elems

  cvt_f32_bf16<<<3584, 256, 0, stream>>>(x, xb, NX, w_qkv, wqb);

  // GEMM1: qkv = x @ W_qkv^T ; Q (pre-scaled), K -> qk, V -> vt transposed
  gemm3<128, true, true, false><<<(M / 128) * (3072 / 128), 256, 0, stream>>>(
      xb, (const void*)wqb, (void*)qk, vt, M, 3072, 1024);

  // causal attention (R10-proven schedule, pre-scaled Q)
  attn_causal10<<<1024, 256, 0, stream>>>(qk, vt, attn);

  // GEMM2: out = attn @ W_o^T (BN=64 tiles: 512 blocks)
  gemm3<64, false, false, true><<<(M / 128) * (1024 / 64), 256, 0, stream>>>(
      attn, (const void*)w_o, (void*)out, nullptr, M, 1024, 1024);
}

// Round 18
// 119.173 us; speedup vs baseline: 1.0840x; 1.0024x over previous
//
#include <hip/hip_runtime.h>
#include <hip/hip_bf16.h>

typedef __bf16 bf16x8 __attribute__((ext_vector_type(8)));
typedef float f32x4 __attribute__((ext_vector_type(4)));
typedef unsigned int u32;
typedef u32 u32x4 __attribute__((ext_vector_type(4)));

#define MFMA(a, b, c) __builtin_amdgcn_mfma_f32_16x16x32_bf16((a), (b), (c), 0, 0, 0)

static __device__ __forceinline__ bf16x8 ld8(const __bf16* p) {
  return *reinterpret_cast<const bf16x8*>(p);
}

// pack two f32 -> bf16x2 in one u32 (compiler fuses to v_cvt_pk_bf16_f32)
static __device__ __forceinline__ u32 pkbf(float a, float b) {
  union { __bf16 h; unsigned short s; } x, y;
  x.h = (__bf16)a; y.h = (__bf16)b;
  return (u32)x.s | ((u32)y.s << 16);
}

// async global->LDS, 16B per lane; LDS dest is wave-uniform base + lane*16
typedef unsigned int __attribute__((address_space(1))) gu32_t;
typedef unsigned int __attribute__((address_space(3))) lu32_t;
static __device__ __forceinline__ void gld16(const __bf16* g, __bf16* l) {
  __builtin_amdgcn_global_load_lds((const gu32_t*)(const void*)g,
                                   (lu32_t*)(void*)l, 16, 0, 0);
}

// fp32 -> bf16 conversion for x and W_qkv (exact-fit into d_out region)
__global__ __launch_bounds__(256)
void cvt_f32_bf16(const float* __restrict__ a, __bf16* __restrict__ oa, int na,
                  const float* __restrict__ b, __bf16* __restrict__ ob) {
  const int i = blockIdx.x * 256 + threadIdx.x;  // one 8-elem chunk per thread
  const float* src; __bf16* dst; int e;
  if (i < (na >> 3)) { src = a; dst = oa; e = i << 3; }
  else { src = b; dst = ob; e = (i << 3) - na; }
  f32x4 v0 = *reinterpret_cast<const f32x4*>(src + e);
  f32x4 v1 = *reinterpret_cast<const f32x4*>(src + e + 4);
  bf16x8 o;
#pragma unroll
  for (int j = 0; j < 4; ++j) { o[j] = (__bf16)v0[j]; o[j + 4] = (__bf16)v1[j]; }
  *reinterpret_cast<bf16x8*>(dst + e) = o;
}

// 8 fp32 -> 8 bf16 LDS write (16B)
static __device__ __forceinline__ void stage8f(__bf16* __restrict__ dst,
                                               const float* __restrict__ src) {
  f32x4 a = *reinterpret_cast<const f32x4*>(src);
  f32x4 b = *reinterpret_cast<const f32x4*>(src + 4);
  bf16x8 o;
#pragma unroll
  for (int i = 0; i < 4; ++i) { o[i] = (__bf16)a[i]; o[i + 4] = (__bf16)b[i]; }
  *reinterpret_cast<bf16x8*>(dst) = o;
}

// C[m][n] = sum_k A[m][k] * W[n][k]  (A @ W^T).  BM=128, BK=64, BN template.
// A bf16 via global_load_lds(16B), pre-swizzled source (chunk ^= row&7).
// W: bf16 via gld16 (same swizzle) or fp32 via reg-stage + swizzled ds_write.
// 4 waves 2x2; wave tile 64 x BN/2. XCD-aware bijective block swizzle
// (grid%8==0): panel-sharing blocks land on the same XCD L2.
// SPLIT (GEMM1): Q cols scaled by SC2Q;
// cols [0,2048) -> QK buf; [2048,3072) -> VT[b*1024+col-2048][t].
template<int BN, bool SPLIT, bool OUT_BF16, bool B_F32>
__global__ __launch_bounds__(256, 2)
void gemm3(const __bf16* __restrict__ A, const void* __restrict__ Wv,
           void* __restrict__ Cv, __bf16* __restrict__ VT,
           int M, int N, int K) {
  constexpr int NF = BN / 32;  // B frags per wave per kc
  constexpr float SC2Q = 0.125f * 1.4426950408889634f;
  __shared__ __bf16 lA[128 * 64];
  __shared__ __bf16 lB[BN * 64];

  const int tid = threadIdx.x;
  const int ntiles = N / BN;
  // XCD-aware bijective swizzle (T1): valid because gridDim.x % 8 == 0
  const int per = gridDim.x >> 3;
  const int bid = (blockIdx.x & 7) * per + (blockIdx.x >> 3);
  const int mt = bid / ntiles;
  const int nt = bid % ntiles;
  const int m0 = mt << 7, n0 = nt * BN;
  const int lane = tid & 63, w = tid >> 6;
  const int wm = (w >> 1) << 6;
  const int wn = (w & 1) * (BN / 2);
  const int fr = lane & 15, fg = lane >> 4;

  f32x4 acc[4][NF] = {};

  for (int k0 = 0; k0 < K; k0 += 64) {
    __syncthreads();
#pragma unroll
    for (int jj = 0; jj < 4; ++jj) {
      const int q = (w << 2) | jj;
      const int v = (q << 6) | lane;
      const int row = v >> 3;
      const int cc = (v & 7) ^ (row & 7);
      gld16(A + (size_t)(m0 + row) * K + k0 + (cc << 3), lA + (q << 9));
    }
    if constexpr (B_F32) {
#pragma unroll
      for (int hh = 0; hh < BN / 64; ++hh) {
        const int row = (tid >> 2) + (hh << 6);
        const int c0 = (tid & 3) << 1;
        const float* src = (const float*)Wv + (size_t)(n0 + row) * K + k0 + (c0 << 3);
#pragma unroll
        for (int cg = 0; cg < 2; ++cg)
          stage8f(lB + (row << 6) + (((c0 + cg) ^ (row & 7)) << 3), src + (cg << 3));
      }
    } else {
#pragma unroll
      for (int jj = 0; jj < NF; ++jj) {
        const int q = w * NF + jj;
        const int v = (q << 6) | lane;
        const int row = v >> 3;
        const int cc = (v & 7) ^ (row & 7);
        gld16((const __bf16*)Wv + (size_t)(n0 + row) * K + k0 + (cc << 3), lB + (q << 9));
      }
    }
    __syncthreads();

    bf16x8 af[2][4], bfr[2][NF];
#pragma unroll
    for (int kc = 0; kc < 2; ++kc) {
#pragma unroll
      for (int m = 0; m < 4; ++m) {
        const int row = wm + m * 16 + fr;
        af[kc][m] = ld8(lA + (row << 6) + ((((kc << 2) | fg) ^ (row & 7)) << 3));
      }
#pragma unroll
      for (int n = 0; n < NF; ++n) {
        const int row = wn + n * 16 + fr;
        bfr[kc][n] = ld8(lB + (row << 6) + ((((kc << 2) | fg) ^ (row & 7)) << 3));
      }
    }
#pragma unroll
    for (int kc = 0; kc < 2; ++kc)
#pragma unroll
      for (int m = 0; m < 4; ++m)
#pragma unroll
        for (int n = 0; n < NF; ++n)
          acc[m][n] = MFMA(af[kc][m], bfr[kc][n], acc[m][n]);
  }

  // C/D layout: col = lane&15, row = (lane>>4)*4 + reg
#pragma unroll
  for (int m = 0; m < 4; ++m) {
#pragma unroll
    for (int n = 0; n < NF; ++n) {
#pragma unroll
      for (int r = 0; r < 4; ++r) {
        int row = m0 + wm + m * 16 + fg * 4 + r;
        int col = n0 + wn + n * 16 + fr;
        float v = acc[m][n][r];
        if constexpr (SPLIT) {
          int b = row >> 11, t = row & 2047;
          if (col >= 2048) {
            VT[((size_t)(b << 10) + (col - 2048)) * 2048 + t] = (__bf16)v;
          } else {
            if (col < 1024) v *= SC2Q;  // pre-scale Q for attention
            ((__bf16*)Cv)[(size_t)row * 2048 + col] = (__bf16)v;
          }
        } else if constexpr (OUT_BF16) {
          ((__bf16*)Cv)[(size_t)row * N + col] = (__bf16)v;
        } else {
          ((float*)Cv)[(size_t)row * N + col] = v;
        }
      }
    }
  }
}

// One online-softmax step for a 64-key tile held as S^T fragments.
// s[n][r] = S[key=k0+n*16+fg*4+r][q=q0wt+fr] (already scaled, log2 domain).
static __device__ __forceinline__ void softmax_step(
    f32x4 (&s)[4], f32x4 (&o)[4], float& m, float& l, bf16x8 (&pa)[2],
    bool diag, int q0wt, int k0, int fg, int fr) {
  constexpr float NEG = -1e30f;
  float sv[4][4];
#pragma unroll
  for (int n = 0; n < 4; ++n)
#pragma unroll
    for (int r = 0; r < 4; ++r) {
      float x = s[n][r];
      if (diag && (k0 + n * 16 + fg * 4 + r > q0wt + fr)) x = NEG;
      sv[n][r] = x;
    }

  float t0 = fmaxf(fmaxf(sv[0][0], sv[0][1]), fmaxf(sv[0][2], sv[0][3]));
  float t1 = fmaxf(fmaxf(sv[1][0], sv[1][1]), fmaxf(sv[1][2], sv[1][3]));
  float t2 = fmaxf(fmaxf(sv[2][0], sv[2][1]), fmaxf(sv[2][2], sv[2][3]));
  float t3 = fmaxf(fmaxf(sv[3][0], sv[3][1]), fmaxf(sv[3][2], sv[3][3]));
  float rm = fmaxf(fmaxf(t0, t1), fmaxf(t2, t3));
  rm = fmaxf(rm, __shfl_xor(rm, 16));
  rm = fmaxf(rm, __shfl_xor(rm, 32));

  // defer-max (T13): rescale only when tile max pushes past m+16
  if (!__all(rm <= m + 16.f)) {
    float mnew = fmaxf(m, rm);
    float alpha = __builtin_exp2f(m - mnew);
    m = mnew;
    l *= alpha;
    float ao[4];
#pragma unroll
    for (int r = 0; r < 4; ++r)
      ao[r] = __shfl(alpha, fg * 4 + r);
#pragma unroll
    for (int n = 0; n < 4; ++n)
#pragma unroll
      for (int r = 0; r < 4; ++r)
        o[n][r] *= ao[r];
  }

  float p[4][4];
#pragma unroll
  for (int n = 0; n < 4; ++n)
#pragma unroll
    for (int r = 0; r < 4; ++r)
      p[n][r] = __builtin_exp2f(sv[n][r] - m);

  float u0 = (p[0][0] + p[0][1]) + (p[0][2] + p[0][3]);
  float u1 = (p[1][0] + p[1][1]) + (p[1][2] + p[1][3]);
  float u2 = (p[2][0] + p[2][1]) + (p[2][2] + p[2][3]);
  float u3 = (p[3][0] + p[3][1]) + (p[3][2] + p[3][3]);
  float rs = (u0 + u1) + (u2 + u3);
  rs += __shfl_xor(rs, 16);
  rs += __shfl_xor(rs, 32);
  l += rs;

  u32 wpk[4][2];
#pragma unroll
  for (int n = 0; n < 4; ++n) {
    wpk[n][0] = pkbf(p[n][0], p[n][1]);
    wpk[n][1] = pkbf(p[n][2], p[n][3]);
  }

  // redistribute P^T -> PV A-fragments (8 bpermutes; bijective instances)
  u32 rcv[2][2][2];
#pragma unroll
  for (int e = 0; e < 2; ++e) {
    const int src = fr + ((((fg & 1) << 1) | ((fg >> 1) ^ e)) << 4);
    const bool tsel = ((fg & 1) ^ e) != 0;
#pragma unroll
    for (int c = 0; c < 2; ++c)
#pragma unroll
      for (int hh = 0; hh < 2; ++hh) {
        u32 v = tsel ? wpk[(c << 1) | 1][hh] : wpk[(c << 1) | 0][hh];
        rcv[e][c][hh] = (u32)__shfl((int)v, src);
      }
  }
  const bool hi = (fg >> 1) != 0;
  u32x4 w0, w1;
#pragma unroll
  for (int a = 0; a < 2; ++a)
#pragma unroll
    for (int hh = 0; hh < 2; ++hh) {
      w0[2 * a + hh] = hi ? rcv[a ^ 1][0][hh] : rcv[a][0][hh];
      w1[2 * a + hh] = hi ? rcv[a ^ 1][1][hh] : rcv[a][1][hh];
    }
  pa[0] = __builtin_bit_cast(bf16x8, w0);
  pa[1] = __builtin_bit_cast(bf16x8, w1);
}

static __device__ __forceinline__ void write_out(
    __bf16* __restrict__ out, f32x4 (&o)[4], float l,
    int b, int hoff, int q0wt, int fg, int fr) {
  float linv = 1.f / l;
  float lo[4];
#pragma unroll
  for (int r = 0; r < 4; ++r)
    lo[r] = __shfl(linv, fg * 4 + r);
#pragma unroll
  for (int n = 0; n < 4; ++n)
#pragma unroll
    for (int r = 0; r < 4; ++r) {
      int t = q0wt + fg * 4 + r;
      out[((size_t)(b * 2048 + t)) * 1024 + hoff + n * 16 + fr] = (__bf16)(o[n][r] * lo[r]);
    }
}

// FA2-style causal flash attention (R10-proven schedule; Q pre-scaled).
// qk: (B*T, 2048) bf16, col = s(0=Q,1=K)*1024 + h*64 + dk (Q pre-scaled).
// vt: (B*1024, 2048) bf16 = V^T per (b,h): row b*1024 + h*64 + dk, col = t.
// Grid: 1024 blocks x 256. Block = (qb, bh): 64 q-rows, wave w owns rows
// [qb*64 + w*16, +16). K/V^T tiles (64x64 each) double-buffered in LDS via
// global_load_lds, chunk-XOR swizzled. One __syncthreads per tile;
// STAGE(next) issued before compute. In-register softmax via swapped QK^T.
// qb comes from a SNAKE map over band bb = (blk>>3)>>2: the 4 bands that
// round-robin onto one CU {g, g+8, g+16, g+24} get qb {31-g, 16+g, 15-g, g}
// -> 66 iterations total on EVERY CU (was 80-4g: 35% per-CU imbalance).
__global__ __launch_bounds__(256, 4)
void attn_causal18(const __bf16* __restrict__ qk, const __bf16* __restrict__ vt,
                   __bf16* __restrict__ out) {
  constexpr float NEG = -1e30f;

  __shared__ __bf16 lK[2][4096];  // [buf][key(64) x dkchunk(8) x 8]
  __shared__ __bf16 lV[2][4096];  // [buf][dk(64) x keychunk(8) x 8]

  const int tid = threadIdx.x;
  const int lane = tid & 63, w = tid >> 6;
  const int fr = lane & 15, fg = lane >> 4;
  const int blk = blockIdx.x;
  const int j = blk >> 3;
  const int bh = ((blk & 7) << 2) | (j & 3);  // XCD-local bh group
  const int bb = j >> 2;                      // band 0..31
  // snake map (bijective): per-CU balanced workload
  int qb;
  if (bb < 8) qb = 31 - bb;
  else if (bb < 16) qb = bb + 8;
  else if (bb < 24) qb = 31 - bb;
  else qb = bb - 24;
  const int b = bh >> 4, h = bh & 15;
  const int q0w = (qb << 6) + (w << 4);       // this wave's q base
  const int hoff = h * 64;
  const size_t qkbase = (size_t)b * (2048 * 2048);
  const __bf16* kb = qk + qkbase + 1024 + hoff;                // K rows, stride 2048
  const __bf16* vtb = vt + (size_t)((b << 10) | hoff) * 2048;  // V^T rows, stride 2048

  // Q fragments (B-operand): col = fr = q-row, k = c*32 + fg*8 + i
  bf16x8 qf[2];
#pragma unroll
  for (int c = 0; c < 2; ++c)
    qf[c] = ld8(qk + qkbase + (size_t)(q0w + fr) * 2048 + hoff + c * 32 + fg * 8);

  f32x4 o[4] = {};
  float m = NEG;
  float l = 0.f;

#define STAGE(bf, k0s)                                                        \
  do {                                                                        \
    _Pragma("unroll")                                                         \
    for (int jj = 0; jj < 2; ++jj) {                                          \
      const int q = (w << 1) | jj;                                            \
      const int v = (q << 6) | lane;                                          \
      const int row = v >> 3;                                                 \
      const int cc = (v & 7) ^ (row & 7);                                     \
      gld16(kb + (size_t)((k0s) + row) * 2048 + (cc << 3), &lK[bf][q << 9]);  \
      gld16(vtb + (size_t)row * 2048 + (k0s) + (cc << 3), &lV[bf][q << 9]);   \
    }                                                                         \
  } while (0)

  int buf = 0;
  STAGE(0, 0);
  __syncthreads();

  for (int kt = 0; kt <= qb; ++kt) {
    const int k0 = kt << 6;
    if (kt < qb) STAGE(buf ^ 1, k0 + 64);  // prefetch next tile (other buffer)

    // QK on LDS K: s[n][r] = S[key=k0+n*16+fg*4+r][q=q0w+fr] (pre-scaled)
    f32x4 s[4] = {};
#pragma unroll
    for (int c = 0; c < 2; ++c) {
      bf16x8 kfc[4];
#pragma unroll
      for (int n = 0; n < 4; ++n) {
        const int row = n * 16 + fr;
        const int sc = ((c << 2) | fg) ^ (row & 7);
        kfc[n] = ld8(&lK[buf][(row << 6) + (sc << 3)]);
      }
#pragma unroll
      for (int n = 0; n < 4; ++n)
        s[n] = MFMA(kfc[n], qf[c], s[n]);
    }

    bf16x8 pa[2];
    softmax_step(s, o, m, l, pa, kt == qb, q0w, k0, fg, fr);

    // O += P V from LDS V^T: B-frag row = dk = n*16+fr, key chunk = c*4+fg
#pragma unroll
    for (int c = 0; c < 2; ++c) {
      bf16x8 vfc[4];
#pragma unroll
      for (int n = 0; n < 4; ++n) {
        const int row = n * 16 + fr;
        const int sc = ((c << 2) | fg) ^ (row & 7);
        vfc[n] = ld8(&lV[buf][(row << 6) + (sc << 3)]);
      }
#pragma unroll
      for (int n = 0; n < 4; ++n)
        o[n] = MFMA(pa[c], vfc[n], o[n]);
    }

    __syncthreads();  // all waves done reading buf; vmcnt drained (next staged)
    buf ^= 1;
  }
#undef STAGE

  write_out(out, o, l, b, hoff, q0w, fg, fr);
}

extern "C" void kernel_launch(void* const* d_in, const int* in_sizes, int n_in,
                              void* d_out, int out_size, void* d_ws, size_t ws_size,
                              hipStream_t stream) {
  const float* x = (const float*)d_in[0];       // (2,2048,1024) fp32
  const float* w_qkv = (const float*)d_in[1];   // (3072,1024) fp32
  const float* w_o = (const float*)d_in[2];     // (1024,1024) fp32
  float* out = (float*)d_out;                   // (2,2048,1024) fp32

  const int M = 4096;  // B*T
  __bf16* qk = (__bf16*)d_ws;                                    // 4096 x 2048 bf16 (16MB)
  __bf16* vt = (__bf16*)((char*)d_ws + (size_t)M * 2048 * 2);    // 2048 x 2048 bf16 (8MB)
  __bf16* attn = (__bf16*)((char*)d_ws + (size_t)M * 3072 * 2);  // 4096 x 1024 bf16 (8MB)

  // bf16 copies of x and W_qkv live in d_out (dead until GEMM2 writes it)
  __bf16* xb = (__bf16*)d_out;
  __bf16* wqb = xb + 4194304;
  const int NX = 4194304;  // x elems

  cvt_f32_bf16<<<3584, 256, 0, stream>>>(x, xb, NX, w_qkv, wqb);

  // GEMM1: qkv = x @ W_qkv^T ; Q (pre-scaled), K -> qk, V -> vt transposed
  gemm3<128, true, true, false><<<(M / 128) * (3072 / 128), 256, 0, stream>>>(
      xb, (const void*)wqb, (void*)qk, vt, M, 3072, 1024);

  // causal attention (R10 schedule + snake-balanced qb map)
  attn_causal18<<<1024, 256, 0, stream>>>(qk, vt, attn);

  // GEMM2: out = attn @ W_o^T (BN=64 tiles: 512 blocks)
  gemm3<64, false, false, true><<<(M / 128) * (1024 / 64), 256, 0, stream>>>(
      attn, (const void*)w_o, (void*)out, nullptr, M, 1024, 1024);
}